// Round 2
// baseline (284.450 us; speedup 1.0000x reference)
//
#include <hip/hip_runtime.h>
#include <hip/hip_bf16.h>
#include <math.h>

// ---------------------------------------------------------------------------
// Mamba block (TimeOnlyMambaBlock): B=4, L=2048, D_MODEL=256, D_INNER=512,
// D_STATE=16, DT_RANK=16, D_CONV=4. All f32 I/O; bf16 MFMA for the GEMMs.
//
// Pipeline (R1):
//  K0 prep     : f32->bf16 of x, in_proj_w, out_proj_w, padded x_proj_w ; A2
//  K1 gemm_bt  : xz[8192,1024] = x @ in_proj_w^T             (bf16 MFMA)
//  K2 conv     : causal dwconv(k=4)+silu sliding-window -> xc (f32) + xcbf
//  K3 gemm_bt  : xd[8192,64] = xcbf @ xproj_w_pad^T          (bf16 MFMA)
//  K4 scanA    : dt inline (LDS-staged xd); per-chunk P=prod(a), h_end
//  K5 scanB    : scan 64 chunk states per (b,d,s); h_init overwrites P
//  K6 scanC    : dt inline; replay from h_init; y=(<h,C>+xc*D)*silu(z) -> ybf
//  K7 gemm_bt  : y2[8192,256] = ybf @ out_proj_w^T           (bf16 MFMA)
//  K8 ln2x     : x1=LN1(y2); x2=LN2(x+x1)
//  K9 enhance  : grouped conv(k=3,groups=4)+BN(eval)+GELU(erf)+residual
// ---------------------------------------------------------------------------

typedef __attribute__((ext_vector_type(8))) short short8;
typedef __attribute__((ext_vector_type(4))) float f32x4;
typedef unsigned short ushortT;

#define NB    4
#define LSEQ  2048
#define DMODEL 256
#define DINNER 512
#define DSTATE 16
#define NTOK  8192
#define NCHUNK 64
#define CT    32        // chunk length (NCHUNK*CT == LSEQ)

// ---------------- K0: prep (bf16 conversions + A2 + padded x_proj_w) -------
__global__ __launch_bounds__(256) void k_prep(
    const float* __restrict__ x, const float* __restrict__ w_in,
    const float* __restrict__ w_out, const float* __restrict__ A_log,
    const float* __restrict__ xproj_w,
    __hip_bfloat16* __restrict__ xbf, __hip_bfloat16* __restrict__ wibf,
    __hip_bfloat16* __restrict__ wobf, float* __restrict__ A2,
    __hip_bfloat16* __restrict__ xpbf) {
  int i = blockIdx.x * 256 + threadIdx.x;
  if (i < NTOK * DMODEL)   xbf[i]  = __float2bfloat16(x[i]);
  if (i < 1024 * DMODEL)   wibf[i] = __float2bfloat16(w_in[i]);
  if (i < DMODEL * DINNER) wobf[i] = __float2bfloat16(w_out[i]);
  if (i < DINNER * DSTATE) A2[i]   = -__expf(A_log[i]);
  if (i < 64 * 512) {
    int row = i >> 9, col = i & 511;
    xpbf[i] = __float2bfloat16(row < 48 ? xproj_w[row * 512 + col] : 0.0f);
  }
}

// ---------------- K1/K3/K7: bf16 MFMA GEMM, C[M,N] = A[M,K] @ W[N,K]^T -----
// 64x64 tile, BK=64 staged, 4 waves: wave w -> n-block w, 4 m-blocks each.
__global__ __launch_bounds__(256) void gemm_bt(
    const ushortT* __restrict__ A, const ushortT* __restrict__ W,
    float* __restrict__ C, int M, int N, int K) {
  __shared__ ushortT Al[64 * 72];
  __shared__ ushortT Wl[64 * 72];
  int tid  = threadIdx.x;
  int mBase = blockIdx.x * 64, nBase = blockIdx.y * 64;
  int wv = tid >> 6, lane = tid & 63, lo = lane & 15, quad = lane >> 4;
  f32x4 acc[4] = {};
  for (int kt = 0; kt < K; kt += 64) {
#pragma unroll
    for (int q = 0; q < 2; ++q) {
      int cid = tid + q * 256;
      int r = cid >> 3, kc = (cid & 7) * 8;
      *(short8*)&Al[r * 72 + kc] = *(const short8*)&A[(size_t)(mBase + r) * K + kt + kc];
      *(short8*)&Wl[r * 72 + kc] = *(const short8*)&W[(size_t)(nBase + r) * K + kt + kc];
    }
    __syncthreads();
#pragma unroll
    for (int k0 = 0; k0 < 64; k0 += 32) {
      short8 bfrag = *(short8*)&Wl[(wv * 16 + lo) * 72 + k0 + quad * 8];
#pragma unroll
      for (int mb = 0; mb < 4; ++mb) {
        short8 afrag = *(short8*)&Al[(mb * 16 + lo) * 72 + k0 + quad * 8];
        acc[mb] = __builtin_amdgcn_mfma_f32_16x16x32_bf16(afrag, bfrag, acc[mb], 0, 0, 0);
      }
    }
    __syncthreads();
  }
#pragma unroll
  for (int mb = 0; mb < 4; ++mb)
#pragma unroll
    for (int r = 0; r < 4; ++r) {
      int row = mBase + mb * 16 + quad * 4 + r;
      int col = nBase + wv * 16 + lo;
      C[(size_t)row * N + col] = acc[mb][r];
    }
}

// ---------------- K2: causal dwconv(k=4)+silu, sliding window --------------
// grid (64 tchunks, 4 b) x 512 threads; thread = channel d, walks 32 tokens.
__global__ __launch_bounds__(512) void k_conv(
    const float* __restrict__ xz, const float* __restrict__ conv_w,
    const float* __restrict__ conv_b,
    float* __restrict__ xc, __hip_bfloat16* __restrict__ xcbf) {
  int d = threadIdx.x;
  int t0 = blockIdx.x * CT, b = blockIdx.y;
  const float* base = xz + (size_t)b * LSEQ * 1024 + d;
  float4 w4 = *(const float4*)&conv_w[d * 4];
  float cb = conv_b[d];
  float xm3, xm2, xm1;
  if (t0 == 0) { xm3 = xm2 = xm1 = 0.0f; }
  else {
    xm3 = base[(size_t)(t0 - 3) * 1024];
    xm2 = base[(size_t)(t0 - 2) * 1024];
    xm1 = base[(size_t)(t0 - 1) * 1024];
  }
  size_t orow = (size_t)(b * LSEQ + t0) * 512 + d;
#pragma unroll 4
  for (int i = 0; i < CT; ++i) {
    float xt = base[(size_t)(t0 + i) * 1024];
    float acc = cb + w4.x * xm3 + w4.y * xm2 + w4.z * xm1 + w4.w * xt;
    float s = acc / (1.0f + __expf(-acc));
    xc[orow] = s;
    xcbf[orow] = __float2bfloat16(s);
    orow += 512;
    xm3 = xm2; xm2 = xm1; xm1 = xt;
  }
}

// ---------------- K4: scan phase A (dt inline; per-chunk P and h_end) ------
// grid (64 chunks, 4 b) x 512 threads; thread = channel d.
__global__ __launch_bounds__(512) void k_scanA(
    const float* __restrict__ xc, const float* __restrict__ xd,
    const float* __restrict__ A2, const float* __restrict__ dtw,
    const float* __restrict__ dtb_,
    float* __restrict__ Pbuf, float* __restrict__ Hend) {
  __shared__ float xdl[CT * 68];
  int tid = threadIdx.x;
  int c = blockIdx.x, b = blockIdx.y;
  int tok0 = b * LSEQ + c * CT;
#pragma unroll
  for (int i = 0; i < 4; ++i) {
    int idx = tid + i * 512;
    int row = idx >> 6, col = idx & 63;
    xdl[row * 68 + col] = xd[(size_t)(tok0 + row) * 64 + col];
  }
  __syncthreads();
  int d = tid;
  float wr[16];
#pragma unroll
  for (int r = 0; r < 16; ++r) wr[r] = dtw[d * 16 + r];
  float bias = dtb_[d];
  float a2[16], P[16], h[16];
#pragma unroll
  for (int s = 0; s < 16; ++s) { a2[s] = A2[d * 16 + s]; P[s] = 1.0f; h[s] = 0.0f; }
  for (int t = 0; t < CT; ++t) {
    float draw = bias;
#pragma unroll
    for (int r = 0; r < 16; ++r) draw += wr[r] * xdl[t * 68 + r];
    float dtv = (draw > 15.0f) ? draw : log1pf(__expf(draw));
    float xv = xc[(size_t)(tok0 + t) * 512 + d];
    float ux = dtv * xv;
#pragma unroll
    for (int s = 0; s < 16; ++s) {
      float a = __expf(dtv * a2[s]);
      h[s] = a * h[s] + ux * xdl[t * 68 + 16 + s];
      P[s] *= a;
    }
  }
  size_t basei = ((size_t)(b * 64 + c) * 512 + d) * 16;
#pragma unroll
  for (int q = 0; q < 4; ++q) {
    *(float4*)&Pbuf[basei + q * 4] = make_float4(P[q*4], P[q*4+1], P[q*4+2], P[q*4+3]);
    *(float4*)&Hend[basei + q * 4] = make_float4(h[q*4], h[q*4+1], h[q*4+2], h[q*4+3]);
  }
}

// ---------------- K5: scan phase B (across chunks; h_init written over P) --
__global__ __launch_bounds__(256) void k_scanB(
    float* __restrict__ Pbuf, const float* __restrict__ Hend) {
  int gid = blockIdx.x * 256 + threadIdx.x;     // 32768 = 4*512*16
  int b = gid >> 13, rem = gid & 8191;
  float carry = 0.f;
  for (int c = 0; c < NCHUNK; ++c) {
    size_t idx = (size_t)(b * 64 + c) * 8192 + rem;
    float p  = Pbuf[idx];
    float he = Hend[idx];
    Pbuf[idx] = carry;
    carry = p * carry + he;
  }
}

// ---------------- K6: scan phase C (dt inline; replay + y + skip + gate) ---
__global__ __launch_bounds__(512) void k_scanC(
    const float* __restrict__ xc, const float* __restrict__ xd,
    const float* __restrict__ A2, const float* __restrict__ dtw,
    const float* __restrict__ dtb_, const float* __restrict__ Hinit,
    const float* __restrict__ xz, const float* __restrict__ Dp,
    __hip_bfloat16* __restrict__ ybf) {
  __shared__ float xdl[CT * 68];
  int tid = threadIdx.x;
  int c = blockIdx.x, b = blockIdx.y;
  int tok0 = b * LSEQ + c * CT;
#pragma unroll
  for (int i = 0; i < 4; ++i) {
    int idx = tid + i * 512;
    int row = idx >> 6, col = idx & 63;
    xdl[row * 68 + col] = xd[(size_t)(tok0 + row) * 64 + col];
  }
  __syncthreads();
  int d = tid;
  float wr[16];
#pragma unroll
  for (int r = 0; r < 16; ++r) wr[r] = dtw[d * 16 + r];
  float bias = dtb_[d];
  float a2[16], h[16];
#pragma unroll
  for (int s = 0; s < 16; ++s) a2[s] = A2[d * 16 + s];
  size_t basei = ((size_t)(b * 64 + c) * 512 + d) * 16;
#pragma unroll
  for (int q = 0; q < 4; ++q) {
    float4 hv = *(const float4*)&Hinit[basei + q * 4];
    h[q*4] = hv.x; h[q*4+1] = hv.y; h[q*4+2] = hv.z; h[q*4+3] = hv.w;
  }
  float dpv = Dp[d];
  for (int t = 0; t < CT; ++t) {
    float draw = bias;
#pragma unroll
    for (int r = 0; r < 16; ++r) draw += wr[r] * xdl[t * 68 + r];
    float dtv = (draw > 15.0f) ? draw : log1pf(__expf(draw));
    float xv = xc[(size_t)(tok0 + t) * 512 + d];
    float zv = xz[(size_t)(tok0 + t) * 1024 + 512 + d];
    float ux = dtv * xv;
    float y = 0.f;
#pragma unroll
    for (int s = 0; s < 16; ++s) {
      float a = __expf(dtv * a2[s]);
      h[s] = a * h[s] + ux * xdl[t * 68 + 16 + s];
      y += h[s] * xdl[t * 68 + 32 + s];
    }
    y = (y + xv * dpv) * (zv / (1.0f + __expf(-zv)));
    ybf[(size_t)(tok0 + t) * 512 + d] = __float2bfloat16(y);
  }
}

// ---------------- K8: two fused LayerNorms (wave per token) ----------------
__global__ __launch_bounds__(256) void k_ln2(
    const float* __restrict__ y2, const float* __restrict__ x,
    const float* __restrict__ g1, const float* __restrict__ b1,
    const float* __restrict__ g2, const float* __restrict__ b2,
    float* __restrict__ x2) {
  int wv = threadIdx.x >> 6, lane = threadIdx.x & 63;
  int tok = blockIdx.x * 4 + wv;
  float4 v = ((const float4*)&y2[(size_t)tok * DMODEL])[lane];
  float s = v.x + v.y + v.z + v.w;
#pragma unroll
  for (int off = 32; off; off >>= 1) s += __shfl_xor(s, off);
  float m = s * (1.0f / DMODEL);
  float4 dv = make_float4(v.x - m, v.y - m, v.z - m, v.w - m);
  float q = dv.x*dv.x + dv.y*dv.y + dv.z*dv.z + dv.w*dv.w;
#pragma unroll
  for (int off = 32; off; off >>= 1) q += __shfl_xor(q, off);
  float rs = rsqrtf(q * (1.0f / DMODEL) + 1e-5f);
  float4 gg = ((const float4*)g1)[lane], bb = ((const float4*)b1)[lane];
  float4 xv = ((const float4*)&x[(size_t)tok * DMODEL])[lane];
  float4 t;
  t.x = xv.x + dv.x * rs * gg.x + bb.x;
  t.y = xv.y + dv.y * rs * gg.y + bb.y;
  t.z = xv.z + dv.z * rs * gg.z + bb.z;
  t.w = xv.w + dv.w * rs * gg.w + bb.w;
  float s2 = t.x + t.y + t.z + t.w;
#pragma unroll
  for (int off = 32; off; off >>= 1) s2 += __shfl_xor(s2, off);
  float m2 = s2 * (1.0f / DMODEL);
  float4 d2 = make_float4(t.x - m2, t.y - m2, t.z - m2, t.w - m2);
  float q2 = d2.x*d2.x + d2.y*d2.y + d2.z*d2.z + d2.w*d2.w;
#pragma unroll
  for (int off = 32; off; off >>= 1) q2 += __shfl_xor(q2, off);
  float rs2 = rsqrtf(q2 * (1.0f / DMODEL) + 1e-5f);
  float4 g2v = ((const float4*)g2)[lane], b2v = ((const float4*)b2)[lane];
  float4 o;
  o.x = d2.x * rs2 * g2v.x + b2v.x;
  o.y = d2.y * rs2 * g2v.y + b2v.y;
  o.z = d2.z * rs2 * g2v.z + b2v.z;
  o.w = d2.w * rs2 * g2v.w + b2v.w;
  ((float4*)&x2[(size_t)tok * DMODEL])[lane] = o;
}

// ---------------- K9: grouped conv(k=3)+BN(eval)+GELU+residual -------------
__global__ __launch_bounds__(256) void k_enh(
    const float* __restrict__ x2, const float* __restrict__ enh_w,
    const float* __restrict__ enh_b, const float* __restrict__ bn_g,
    const float* __restrict__ bn_b, const float* __restrict__ bn_mean,
    const float* __restrict__ bn_var, float* __restrict__ out) {
  __shared__ float xe[130 * 65];
  int tid = threadIdx.x;
  int tb = blockIdx.x, g = blockIdx.y, b = blockIdx.z;
  int tbase = tb * 128;
  for (int idx = tid; idx < 130 * 64; idx += 256) {
    int j = idx >> 6, ci = idx & 63;
    int tg = tbase - 1 + j;
    float v = 0.f;
    if (tg >= 0 && tg < LSEQ) v = x2[(size_t)(b * LSEQ + tg) * DMODEL + g * 64 + ci];
    xe[j * 65 + ci] = v;
  }
  __syncthreads();
  int c = tid & 63, rb = tid >> 6;
  int cg = g * 64 + c;
  float acc[4][8] = {};
  for (int ci = 0; ci < 64; ++ci) {
    float w0 = enh_w[cg * 192 + ci * 3 + 0];
    float w1 = enh_w[cg * 192 + ci * 3 + 1];
    float w2 = enh_w[cg * 192 + ci * 3 + 2];
#pragma unroll
    for (int i = 0; i < 4; ++i) {
      int tl = (i * 4 + rb) * 8;
      float xv[10];
#pragma unroll
      for (int qq = 0; qq < 10; ++qq) xv[qq] = xe[(tl + qq) * 65 + ci];
#pragma unroll
      for (int u = 0; u < 8; ++u)
        acc[i][u] += w0 * xv[u] + w1 * xv[u + 1] + w2 * xv[u + 2];
    }
  }
  float scale = bn_g[cg] * rsqrtf(bn_var[cg] + 1e-5f);
  float shift = bn_b[cg] - bn_mean[cg] * scale;
  float ebv = enh_b[cg];
#pragma unroll
  for (int i = 0; i < 4; ++i) {
    int tl = (i * 4 + rb) * 8;
#pragma unroll
    for (int u = 0; u < 8; ++u) {
      float v = (acc[i][u] + ebv) * scale + shift;
      float ge = 0.5f * v * (1.0f + erff(v * 0.70710678118f));
      int t = tbase + tl + u;
      out[(size_t)(b * LSEQ + t) * DMODEL + cg] = xe[(tl + u + 1) * 65 + c] + ge;
    }
  }
}

// ---------------------------------------------------------------------------
extern "C" void kernel_launch(void* const* d_in, const int* in_sizes, int n_in,
                              void* d_out, int out_size, void* d_ws, size_t ws_size,
                              hipStream_t stream) {
  const float* x        = (const float*)d_in[0];
  const float* in_w     = (const float*)d_in[1];
  const float* conv_w   = (const float*)d_in[2];
  const float* conv_b   = (const float*)d_in[3];
  const float* xproj_w  = (const float*)d_in[4];
  const float* dtproj_w = (const float*)d_in[5];
  const float* dtproj_b = (const float*)d_in[6];
  const float* A_log    = (const float*)d_in[7];
  const float* Dp       = (const float*)d_in[8];
  const float* out_w    = (const float*)d_in[9];
  const float* ln1_g    = (const float*)d_in[10];
  const float* ln1_b    = (const float*)d_in[11];
  const float* ln2_g    = (const float*)d_in[12];
  const float* ln2_b    = (const float*)d_in[13];
  const float* enh_w    = (const float*)d_in[14];
  const float* enh_b    = (const float*)d_in[15];
  const float* bn_g     = (const float*)d_in[16];
  const float* bn_b     = (const float*)d_in[17];
  const float* bn_mean  = (const float*)d_in[18];
  const float* bn_var   = (const float*)d_in[19];
  float* out = (float*)d_out;

  char* ws = (char*)d_ws;
  size_t off = 0;
  auto alloc = [&](size_t bytes) { char* p = ws + off; off += (bytes + 255) & ~(size_t)255; return p; };
  float*          xz   = (float*)alloc((size_t)NTOK * 1024 * 4);     // 32 MB (xin | z)
  float*          xc   = (float*)alloc((size_t)NTOK * 512 * 4);      // 16 MB
  __hip_bfloat16* xcbf = (__hip_bfloat16*)alloc((size_t)NTOK * 512 * 2); // 8 MB
  float*          xd   = (float*)alloc((size_t)NTOK * 64 * 4);       //  2 MB
  float*          A2   = (float*)alloc((size_t)DINNER * DSTATE * 4);
  __hip_bfloat16* xbf  = (__hip_bfloat16*)alloc((size_t)NTOK * DMODEL * 2);
  __hip_bfloat16* wibf = (__hip_bfloat16*)alloc((size_t)1024 * DMODEL * 2);
  __hip_bfloat16* wobf = (__hip_bfloat16*)alloc((size_t)DMODEL * DINNER * 2);
  __hip_bfloat16* xpbf = (__hip_bfloat16*)alloc((size_t)64 * 512 * 2);
  float*          Pb   = (float*)alloc((size_t)NB * 64 * 512 * 16 * 4);  // 8 MB
  float*          He   = (float*)alloc((size_t)NB * 64 * 512 * 16 * 4);  // 8 MB
  __hip_bfloat16* ybf  = (__hip_bfloat16*)alloc((size_t)NTOK * 512 * 2); // 8 MB
  float* y2 = xz;   // out_proj result [8192,256] — xz dead after K6
  float* x2 = xc;   // post-LN2       [8192,256] — xc dead after K6
  (void)ws_size; (void)in_sizes; (void)n_in; (void)out_size;

  k_prep<<<8192, 256, 0, stream>>>(x, in_w, out_w, A_log, xproj_w,
                                   xbf, wibf, wobf, A2, xpbf);
  gemm_bt<<<dim3(128, 16), 256, 0, stream>>>((const ushortT*)xbf, (const ushortT*)wibf,
                                             xz, NTOK, 1024, DMODEL);
  k_conv<<<dim3(64, 4), 512, 0, stream>>>(xz, conv_w, conv_b, xc, xcbf);
  gemm_bt<<<dim3(128, 1), 256, 0, stream>>>((const ushortT*)xcbf, (const ushortT*)xpbf,
                                            xd, NTOK, 64, DINNER);
  k_scanA<<<dim3(64, 4), 512, 0, stream>>>(xc, xd, A2, dtproj_w, dtproj_b, Pb, He);
  k_scanB<<<128, 256, 0, stream>>>(Pb, He);
  k_scanC<<<dim3(64, 4), 512, 0, stream>>>(xc, xd, A2, dtproj_w, dtproj_b, Pb, xz, Dp, ybf);
  gemm_bt<<<dim3(128, 4), 256, 0, stream>>>((const ushortT*)ybf, (const ushortT*)wobf,
                                            y2, NTOK, DMODEL, DINNER);
  k_ln2<<<2048, 256, 0, stream>>>(y2, x, ln1_g, ln1_b, ln2_g, ln2_b, x2);
  k_enh<<<dim3(16, 4, 4), 256, 0, stream>>>(x2, enh_w, enh_b, bn_g, bn_b, bn_mean, bn_var, out);
}

// Round 3
// 262.041 us; speedup vs baseline: 1.0855x; 1.0855x over previous
//
#include <hip/hip_runtime.h>
#include <hip/hip_bf16.h>
#include <math.h>

// ---------------------------------------------------------------------------
// Mamba block (TimeOnlyMambaBlock): B=4, L=2048, D_MODEL=256, D_INNER=512,
// D_STATE=16, DT_RANK=16, D_CONV=4. All f32 I/O; bf16 MFMA for the GEMMs.
//
// Pipeline (R2):
//  K0 prep     : bf16 of x, in_proj_w, out_proj_w, padded x_proj_w ; A2L
//  K1 gemm_bt  : xz[8192,1024] = x @ in_proj_w^T             (bf16 MFMA)
//  K2 conv     : causal dwconv(k=4)+silu sliding-window -> xc (f32) + xcbf
//  K3 gemm_bt  : xd[8192,64] = xcbf @ xproj_w_pad^T          (bf16 MFMA)
//  K4 scanA    : dt once (fast softplus, stored); sdt + h_end per 16-chunk
//  K5 scanB    : P=exp2(a2l*sdt); scan 128 chunk states; h_init overwrites Hend
//  K6 scanC    : reads dtv; replay from h_init; y=(<h,C>+xc*D)*silu(z) -> ybf
//  K7 gemm_bt  : y2[8192,256] = ybf @ out_proj_w^T           (bf16 MFMA)
//  K8 ln2x     : x1=LN1(y2); x2=LN2(x+x1)
//  K9 enhance  : grouped conv(k=3,groups=4)+BN(eval)+GELU(erf)+residual
// ---------------------------------------------------------------------------

typedef __attribute__((ext_vector_type(8))) short short8;
typedef __attribute__((ext_vector_type(4))) float f32x4;
typedef unsigned short ushortT;

#define NB    4
#define LSEQ  2048
#define DMODEL 256
#define DINNER 512
#define DSTATE 16
#define NTOK  8192
#define NCHUNK 128
#define CT    16        // scan chunk length (NCHUNK*CT == LSEQ)
#define CTC   32        // conv chunk length

// ---------------- K0: prep (bf16 conversions + A2L + padded x_proj_w) ------
__global__ __launch_bounds__(256) void k_prep(
    const float* __restrict__ x, const float* __restrict__ w_in,
    const float* __restrict__ w_out, const float* __restrict__ A_log,
    const float* __restrict__ xproj_w,
    __hip_bfloat16* __restrict__ xbf, __hip_bfloat16* __restrict__ wibf,
    __hip_bfloat16* __restrict__ wobf, float* __restrict__ A2L,
    __hip_bfloat16* __restrict__ xpbf) {
  int i = blockIdx.x * 256 + threadIdx.x;
  if (i < NTOK * DMODEL)   xbf[i]  = __float2bfloat16(x[i]);
  if (i < 1024 * DMODEL)   wibf[i] = __float2bfloat16(w_in[i]);
  if (i < DMODEL * DINNER) wobf[i] = __float2bfloat16(w_out[i]);
  if (i < DINNER * DSTATE) A2L[i]  = -__expf(A_log[i]) * 1.44269504089f; // log2e
  if (i < 64 * 512) {
    int row = i >> 9, col = i & 511;
    xpbf[i] = __float2bfloat16(row < 48 ? xproj_w[row * 512 + col] : 0.0f);
  }
}

// ---------------- K1/K3/K7: bf16 MFMA GEMM, C[M,N] = A[M,K] @ W[N,K]^T -----
__global__ __launch_bounds__(256) void gemm_bt(
    const ushortT* __restrict__ A, const ushortT* __restrict__ W,
    float* __restrict__ C, int M, int N, int K) {
  __shared__ ushortT Al[64 * 72];
  __shared__ ushortT Wl[64 * 72];
  int tid  = threadIdx.x;
  int mBase = blockIdx.x * 64, nBase = blockIdx.y * 64;
  int wv = tid >> 6, lane = tid & 63, lo = lane & 15, quad = lane >> 4;
  f32x4 acc[4] = {};
  for (int kt = 0; kt < K; kt += 64) {
#pragma unroll
    for (int q = 0; q < 2; ++q) {
      int cid = tid + q * 256;
      int r = cid >> 3, kc = (cid & 7) * 8;
      *(short8*)&Al[r * 72 + kc] = *(const short8*)&A[(size_t)(mBase + r) * K + kt + kc];
      *(short8*)&Wl[r * 72 + kc] = *(const short8*)&W[(size_t)(nBase + r) * K + kt + kc];
    }
    __syncthreads();
#pragma unroll
    for (int k0 = 0; k0 < 64; k0 += 32) {
      short8 bfrag = *(short8*)&Wl[(wv * 16 + lo) * 72 + k0 + quad * 8];
#pragma unroll
      for (int mb = 0; mb < 4; ++mb) {
        short8 afrag = *(short8*)&Al[(mb * 16 + lo) * 72 + k0 + quad * 8];
        acc[mb] = __builtin_amdgcn_mfma_f32_16x16x32_bf16(afrag, bfrag, acc[mb], 0, 0, 0);
      }
    }
    __syncthreads();
  }
#pragma unroll
  for (int mb = 0; mb < 4; ++mb)
#pragma unroll
    for (int r = 0; r < 4; ++r) {
      int row = mBase + mb * 16 + quad * 4 + r;
      int col = nBase + wv * 16 + lo;
      C[(size_t)row * N + col] = acc[mb][r];
    }
}

// ---------------- K2: causal dwconv(k=4)+silu, sliding window --------------
__global__ __launch_bounds__(512) void k_conv(
    const float* __restrict__ xz, const float* __restrict__ conv_w,
    const float* __restrict__ conv_b,
    float* __restrict__ xc, __hip_bfloat16* __restrict__ xcbf) {
  int d = threadIdx.x;
  int t0 = blockIdx.x * CTC, b = blockIdx.y;
  const float* base = xz + (size_t)b * LSEQ * 1024 + d;
  float4 w4 = *(const float4*)&conv_w[d * 4];
  float cb = conv_b[d];
  float xm3, xm2, xm1;
  if (t0 == 0) { xm3 = xm2 = xm1 = 0.0f; }
  else {
    xm3 = base[(size_t)(t0 - 3) * 1024];
    xm2 = base[(size_t)(t0 - 2) * 1024];
    xm1 = base[(size_t)(t0 - 1) * 1024];
  }
  size_t orow = (size_t)(b * LSEQ + t0) * 512 + d;
#pragma unroll 4
  for (int i = 0; i < CTC; ++i) {
    float xt = base[(size_t)(t0 + i) * 1024];
    float acc = cb + w4.x * xm3 + w4.y * xm2 + w4.z * xm1 + w4.w * xt;
    float s = acc / (1.0f + __expf(-acc));
    xc[orow] = s;
    xcbf[orow] = __float2bfloat16(s);
    orow += 512;
    xm3 = xm2; xm2 = xm1; xm1 = xt;
  }
}

__device__ __forceinline__ float softplus_fast(float v) {
  return fmaxf(v, 0.0f) + __logf(1.0f + __expf(-fabsf(v)));
}

// ---------------- K4: scan phase A (dt once; sdt + h_end per chunk) --------
// grid (128 chunks, 4 b) x 512 threads; thread = channel d.
__global__ __launch_bounds__(512) void k_scanA(
    const float* __restrict__ xc, const float* __restrict__ xd,
    const float* __restrict__ A2L, const float* __restrict__ dtw,
    const float* __restrict__ dtb_,
    float* __restrict__ dtv_buf, float* __restrict__ Sd,
    float* __restrict__ Hend) {
  __shared__ float xdl[CT * 68];
  int tid = threadIdx.x;
  int c = blockIdx.x, b = blockIdx.y;
  int tok0 = b * LSEQ + c * CT;
#pragma unroll
  for (int i = 0; i < 2; ++i) {
    int idx = tid + i * 512;
    int row = idx >> 6, col = idx & 63;
    xdl[row * 68 + col] = xd[(size_t)(tok0 + row) * 64 + col];
  }
  __syncthreads();
  int d = tid;
  float wr[16];
#pragma unroll
  for (int r = 0; r < 16; ++r) wr[r] = dtw[d * 16 + r];
  float bias = dtb_[d];
  float a2l[16], h[16];
#pragma unroll
  for (int s = 0; s < 16; ++s) { a2l[s] = A2L[d * 16 + s]; h[s] = 0.0f; }
  float sdt = 0.0f;
  for (int t = 0; t < CT; ++t) {
    float draw = bias;
#pragma unroll
    for (int r = 0; r < 16; ++r) draw += wr[r] * xdl[t * 68 + r];
    float dtv = softplus_fast(draw);
    dtv_buf[(size_t)(tok0 + t) * 512 + d] = dtv;
    sdt += dtv;
    float xv = xc[(size_t)(tok0 + t) * 512 + d];
    float ux = dtv * xv;
#pragma unroll
    for (int s = 0; s < 16; ++s) {
      float a = exp2f(dtv * a2l[s]);
      h[s] = a * h[s] + ux * xdl[t * 68 + 16 + s];
    }
  }
  Sd[(size_t)(b * NCHUNK + c) * 512 + d] = sdt;
  size_t basei = ((size_t)(b * NCHUNK + c) * 512 + d) * 16;
#pragma unroll
  for (int q = 0; q < 4; ++q)
    *(float4*)&Hend[basei + q * 4] = make_float4(h[q*4], h[q*4+1], h[q*4+2], h[q*4+3]);
}

// ---------------- K5: scan phase B (P from sdt; h_init overwrites Hend) ----
__global__ __launch_bounds__(256) void k_scanB(
    const float* __restrict__ Sd, float* __restrict__ Hend,
    const float* __restrict__ A2L) {
  int gid = blockIdx.x * 256 + threadIdx.x;     // 32768 = 4*512*16
  int b = gid >> 13, rem = gid & 8191, d = rem >> 4;
  float a2lv = A2L[rem];
  float carry = 0.f;
  for (int c = 0; c < NCHUNK; ++c) {
    float sdt = Sd[(size_t)(b * NCHUNK + c) * 512 + d];
    size_t idx = (size_t)(b * NCHUNK + c) * 8192 + rem;
    float p  = exp2f(a2lv * sdt);
    float he = Hend[idx];
    Hend[idx] = carry;
    carry = p * carry + he;
  }
}

// ---------------- K6: scan phase C (reads dtv; replay + y + skip + gate) ---
__global__ __launch_bounds__(512) void k_scanC(
    const float* __restrict__ xc, const float* __restrict__ xd,
    const float* __restrict__ A2L, const float* __restrict__ dtv_buf,
    const float* __restrict__ Hinit, const float* __restrict__ xz,
    const float* __restrict__ Dp, __hip_bfloat16* __restrict__ ybf) {
  __shared__ float xdl[CT * 68];
  int tid = threadIdx.x;
  int c = blockIdx.x, b = blockIdx.y;
  int tok0 = b * LSEQ + c * CT;
#pragma unroll
  for (int i = 0; i < 2; ++i) {
    int idx = tid + i * 512;
    int row = idx >> 6, col = idx & 63;
    xdl[row * 68 + col] = xd[(size_t)(tok0 + row) * 64 + col];
  }
  __syncthreads();
  int d = tid;
  float a2l[16], h[16];
#pragma unroll
  for (int s = 0; s < 16; ++s) a2l[s] = A2L[d * 16 + s];
  size_t basei = ((size_t)(b * NCHUNK + c) * 512 + d) * 16;
#pragma unroll
  for (int q = 0; q < 4; ++q) {
    float4 hv = *(const float4*)&Hinit[basei + q * 4];
    h[q*4] = hv.x; h[q*4+1] = hv.y; h[q*4+2] = hv.z; h[q*4+3] = hv.w;
  }
  float dpv = Dp[d];
  for (int t = 0; t < CT; ++t) {
    float dtv = dtv_buf[(size_t)(tok0 + t) * 512 + d];
    float xv = xc[(size_t)(tok0 + t) * 512 + d];
    float zv = xz[(size_t)(tok0 + t) * 1024 + 512 + d];
    float ux = dtv * xv;
    float y = 0.f;
#pragma unroll
    for (int s = 0; s < 16; ++s) {
      float a = exp2f(dtv * a2l[s]);
      h[s] = a * h[s] + ux * xdl[t * 68 + 16 + s];
      y += h[s] * xdl[t * 68 + 32 + s];
    }
    y = (y + xv * dpv) * (zv / (1.0f + __expf(-zv)));
    ybf[(size_t)(tok0 + t) * 512 + d] = __float2bfloat16(y);
  }
}

// ---------------- K8: two fused LayerNorms (wave per token) ----------------
__global__ __launch_bounds__(256) void k_ln2(
    const float* __restrict__ y2, const float* __restrict__ x,
    const float* __restrict__ g1, const float* __restrict__ b1,
    const float* __restrict__ g2, const float* __restrict__ b2,
    float* __restrict__ x2) {
  int wv = threadIdx.x >> 6, lane = threadIdx.x & 63;
  int tok = blockIdx.x * 4 + wv;
  float4 v = ((const float4*)&y2[(size_t)tok * DMODEL])[lane];
  float s = v.x + v.y + v.z + v.w;
#pragma unroll
  for (int off = 32; off; off >>= 1) s += __shfl_xor(s, off);
  float m = s * (1.0f / DMODEL);
  float4 dv = make_float4(v.x - m, v.y - m, v.z - m, v.w - m);
  float q = dv.x*dv.x + dv.y*dv.y + dv.z*dv.z + dv.w*dv.w;
#pragma unroll
  for (int off = 32; off; off >>= 1) q += __shfl_xor(q, off);
  float rs = rsqrtf(q * (1.0f / DMODEL) + 1e-5f);
  float4 gg = ((const float4*)g1)[lane], bb = ((const float4*)b1)[lane];
  float4 xv = ((const float4*)&x[(size_t)tok * DMODEL])[lane];
  float4 t;
  t.x = xv.x + dv.x * rs * gg.x + bb.x;
  t.y = xv.y + dv.y * rs * gg.y + bb.y;
  t.z = xv.z + dv.z * rs * gg.z + bb.z;
  t.w = xv.w + dv.w * rs * gg.w + bb.w;
  float s2 = t.x + t.y + t.z + t.w;
#pragma unroll
  for (int off = 32; off; off >>= 1) s2 += __shfl_xor(s2, off);
  float m2 = s2 * (1.0f / DMODEL);
  float4 d2 = make_float4(t.x - m2, t.y - m2, t.z - m2, t.w - m2);
  float q2 = d2.x*d2.x + d2.y*d2.y + d2.z*d2.z + d2.w*d2.w;
#pragma unroll
  for (int off = 32; off; off >>= 1) q2 += __shfl_xor(q2, off);
  float rs2 = rsqrtf(q2 * (1.0f / DMODEL) + 1e-5f);
  float4 g2v = ((const float4*)g2)[lane], b2v = ((const float4*)b2)[lane];
  float4 o;
  o.x = d2.x * rs2 * g2v.x + b2v.x;
  o.y = d2.y * rs2 * g2v.y + b2v.y;
  o.z = d2.z * rs2 * g2v.z + b2v.z;
  o.w = d2.w * rs2 * g2v.w + b2v.w;
  ((float4*)&x2[(size_t)tok * DMODEL])[lane] = o;
}

// ---------------- K9: grouped conv(k=3)+BN(eval)+GELU+residual -------------
__global__ __launch_bounds__(256) void k_enh(
    const float* __restrict__ x2, const float* __restrict__ enh_w,
    const float* __restrict__ enh_b, const float* __restrict__ bn_g,
    const float* __restrict__ bn_b, const float* __restrict__ bn_mean,
    const float* __restrict__ bn_var, float* __restrict__ out) {
  __shared__ float xe[130 * 65];
  int tid = threadIdx.x;
  int tb = blockIdx.x, g = blockIdx.y, b = blockIdx.z;
  int tbase = tb * 128;
  for (int idx = tid; idx < 130 * 64; idx += 256) {
    int j = idx >> 6, ci = idx & 63;
    int tg = tbase - 1 + j;
    float v = 0.f;
    if (tg >= 0 && tg < LSEQ) v = x2[(size_t)(b * LSEQ + tg) * DMODEL + g * 64 + ci];
    xe[j * 65 + ci] = v;
  }
  __syncthreads();
  int c = tid & 63, rb = tid >> 6;
  int cg = g * 64 + c;
  float acc[4][8] = {};
  for (int ci = 0; ci < 64; ++ci) {
    float w0 = enh_w[cg * 192 + ci * 3 + 0];
    float w1 = enh_w[cg * 192 + ci * 3 + 1];
    float w2 = enh_w[cg * 192 + ci * 3 + 2];
#pragma unroll
    for (int i = 0; i < 4; ++i) {
      int tl = (i * 4 + rb) * 8;
      float xv[10];
#pragma unroll
      for (int qq = 0; qq < 10; ++qq) xv[qq] = xe[(tl + qq) * 65 + ci];
#pragma unroll
      for (int u = 0; u < 8; ++u)
        acc[i][u] += w0 * xv[u] + w1 * xv[u + 1] + w2 * xv[u + 2];
    }
  }
  float scale = bn_g[cg] * rsqrtf(bn_var[cg] + 1e-5f);
  float shift = bn_b[cg] - bn_mean[cg] * scale;
  float ebv = enh_b[cg];
#pragma unroll
  for (int i = 0; i < 4; ++i) {
    int tl = (i * 4 + rb) * 8;
#pragma unroll
    for (int u = 0; u < 8; ++u) {
      float v = (acc[i][u] + ebv) * scale + shift;
      float ge = 0.5f * v * (1.0f + erff(v * 0.70710678118f));
      int t = tbase + tl + u;
      out[(size_t)(b * LSEQ + t) * DMODEL + cg] = xe[(tl + u + 1) * 65 + c] + ge;
    }
  }
}

// ---------------------------------------------------------------------------
extern "C" void kernel_launch(void* const* d_in, const int* in_sizes, int n_in,
                              void* d_out, int out_size, void* d_ws, size_t ws_size,
                              hipStream_t stream) {
  const float* x        = (const float*)d_in[0];
  const float* in_w     = (const float*)d_in[1];
  const float* conv_w   = (const float*)d_in[2];
  const float* conv_b   = (const float*)d_in[3];
  const float* xproj_w  = (const float*)d_in[4];
  const float* dtproj_w = (const float*)d_in[5];
  const float* dtproj_b = (const float*)d_in[6];
  const float* A_log    = (const float*)d_in[7];
  const float* Dp       = (const float*)d_in[8];
  const float* out_w    = (const float*)d_in[9];
  const float* ln1_g    = (const float*)d_in[10];
  const float* ln1_b    = (const float*)d_in[11];
  const float* ln2_g    = (const float*)d_in[12];
  const float* ln2_b    = (const float*)d_in[13];
  const float* enh_w    = (const float*)d_in[14];
  const float* enh_b    = (const float*)d_in[15];
  const float* bn_g     = (const float*)d_in[16];
  const float* bn_b     = (const float*)d_in[17];
  const float* bn_mean  = (const float*)d_in[18];
  const float* bn_var   = (const float*)d_in[19];
  float* out = (float*)d_out;

  char* ws = (char*)d_ws;
  size_t off = 0;
  auto alloc = [&](size_t bytes) { char* p = ws + off; off += (bytes + 255) & ~(size_t)255; return p; };
  float*          xz   = (float*)alloc((size_t)NTOK * 1024 * 4);     // 32 MB (xin | z)
  float*          xc   = (float*)alloc((size_t)NTOK * 512 * 4);      // 16 MB
  __hip_bfloat16* xcbf = (__hip_bfloat16*)alloc((size_t)NTOK * 512 * 2); // 8 MB
  float*          xd   = (float*)alloc((size_t)NTOK * 64 * 4);       //  2 MB
  float*          dtv  = (float*)alloc((size_t)NTOK * 512 * 4);      // 16 MB
  float*          A2L  = (float*)alloc((size_t)DINNER * DSTATE * 4);
  __hip_bfloat16* xbf  = (__hip_bfloat16*)alloc((size_t)NTOK * DMODEL * 2);
  __hip_bfloat16* wibf = (__hip_bfloat16*)alloc((size_t)1024 * DMODEL * 2);
  __hip_bfloat16* wobf = (__hip_bfloat16*)alloc((size_t)DMODEL * DINNER * 2);
  __hip_bfloat16* xpbf = (__hip_bfloat16*)alloc((size_t)64 * 512 * 2);
  float*          Sd   = (float*)alloc((size_t)NB * NCHUNK * 512 * 4);       // 1 MB
  float*          He   = (float*)alloc((size_t)NB * NCHUNK * 512 * 16 * 4);  // 16 MB
  __hip_bfloat16* ybf  = (__hip_bfloat16*)alloc((size_t)NTOK * 512 * 2);     // 8 MB
  float* y2 = xz;   // out_proj result [8192,256] — xz dead after K6
  float* x2 = xc;   // post-LN2       [8192,256] — xc dead after K6
  (void)ws_size; (void)in_sizes; (void)n_in; (void)out_size;

  k_prep<<<8192, 256, 0, stream>>>(x, in_w, out_w, A_log, xproj_w,
                                   xbf, wibf, wobf, A2L, xpbf);
  gemm_bt<<<dim3(128, 16), 256, 0, stream>>>((const ushortT*)xbf, (const ushortT*)wibf,
                                             xz, NTOK, 1024, DMODEL);
  k_conv<<<dim3(64, 4), 512, 0, stream>>>(xz, conv_w, conv_b, xc, xcbf);
  gemm_bt<<<dim3(128, 1), 256, 0, stream>>>((const ushortT*)xcbf, (const ushortT*)xpbf,
                                            xd, NTOK, 64, DINNER);
  k_scanA<<<dim3(NCHUNK, 4), 512, 0, stream>>>(xc, xd, A2L, dtproj_w, dtproj_b,
                                               dtv, Sd, He);
  k_scanB<<<128, 256, 0, stream>>>(Sd, He, A2L);
  k_scanC<<<dim3(NCHUNK, 4), 512, 0, stream>>>(xc, xd, A2L, dtv, He, xz, Dp, ybf);
  gemm_bt<<<dim3(128, 4), 256, 0, stream>>>((const ushortT*)ybf, (const ushortT*)wobf,
                                            y2, NTOK, DMODEL, DINNER);
  k_ln2<<<2048, 256, 0, stream>>>(y2, x, ln1_g, ln1_b, ln2_g, ln2_b, x2);
  k_enh<<<dim3(16, 4, 4), 256, 0, stream>>>(x2, enh_w, enh_b, bn_g, bn_b, bn_mean, bn_var, out);
}